// Round 8
// baseline (223.671 us; speedup 1.0000x reference)
//
#include <hip/hip_runtime.h>
#include <cstddef>
#include <cstdint>

// ---------------------------------------------------------------------------
// B=8, N=1024, C=768, H=12, hd=64.  All matmuls mfma_f32_16x16x32_bf16.
// R7: attn gets (1) LDS double-buffered K/V staging (direct-indexed offsets,
// single barrier per K-tile), (2) v_perm packed bf16 conversion for P
// (round-half-up: max 0.5 ulp, 3 insts per 2 values vs 8).  All f2bf sites
// use the 2-inst round-half-up form.  qkv/proj keep R6 structure + swizzle.
// ---------------------------------------------------------------------------

typedef __attribute__((ext_vector_type(4))) float f32x4;
typedef __attribute__((ext_vector_type(8))) __bf16 bf16x8;
typedef __attribute__((ext_vector_type(4))) unsigned int uint4v;
typedef __attribute__((ext_vector_type(2))) unsigned int uint2v;
typedef __attribute__((ext_vector_type(4))) unsigned short ushort4v;

#define QK_PRESCALE 0.18033688011112042f   // 64^-0.5 * log2(e); softmax uses exp2

// round-half-up bf16: max error 0.5 ulp (ties round up instead of to-even)
__device__ __forceinline__ unsigned short f2bf(float f) {
  return (unsigned short)((__float_as_uint(f) + 0x8000u) >> 16);
}
// pack two floats -> bf16x2 in one v_perm_b32: (bf(fhi)<<16) | bf(flo)
__device__ __forceinline__ unsigned int pack2bf(float flo, float fhi) {
  unsigned ulo = __float_as_uint(flo) + 0x8000u;
  unsigned uhi = __float_as_uint(fhi) + 0x8000u;
  return __builtin_amdgcn_perm(uhi, ulo, 0x07060302);
}

// one wave instruction: 64 lanes x 16 B -> LDS[base + lane*16]
__device__ __forceinline__ void gl_lds16(const unsigned short* g, unsigned short* l) {
  __builtin_amdgcn_global_load_lds(
      (const __attribute__((address_space(1))) unsigned int*)g,
      (__attribute__((address_space(3))) unsigned int*)l, 16, 0, 0);
}

// ---------------------------------------------------------------------------
// fp32 -> bf16 conversion, 4 elements/thread
// ---------------------------------------------------------------------------
__global__ __launch_bounds__(256)
void cvt_kernel(const float* __restrict__ src, unsigned short* __restrict__ dst, int n4) {
  int i = blockIdx.x * 256 + threadIdx.x;
  if (i < n4) {
    float4 v = ((const float4*)src)[i];
    uint2v o;
    o.x = pack2bf(v.x, v.y);
    o.y = pack2bf(v.z, v.w);
    ((uint2v*)dst)[i] = o;
  }
}

// ---------------------------------------------------------------------------
// QKV GEMM: M=8192, N=2304, K=768. 128x128 tile, BK=64, 4 waves.
// 1152 blocks = 8 XCD x (18 n-tiles x 8 m-tiles, m fastest).
// q/k tiles (n0 < 1536): operands swapped (A=w, B=x) -> acc rows=d, cols=tok.
// v tiles: unswapped -> acc rows=tok, cols=d.
// Staging XOR-swizzled; epilogue via LDS scratch (stride 136) -> b128 stores.
// ---------------------------------------------------------------------------
__global__ __launch_bounds__(256)
void qkv_gemm(const unsigned short* __restrict__ xb, const unsigned short* __restrict__ wb,
              const float* __restrict__ qb, const float* __restrict__ vb,
              unsigned short* __restrict__ qo, unsigned short* __restrict__ ko,
              unsigned short* __restrict__ vto) {
  __shared__ __align__(16) unsigned short smem[17408];  // as[0..8191] bs[8192..16383]; scratch 128x136
  const int tid = threadIdx.x;
  const int lane = tid & 63, wid = tid >> 6;
  const int lm = lane & 15, lq = lane >> 4;
  const int wm = (wid & 1) * 64, wn = (wid >> 1) * 64;
  const int xsw = lm & 7;                       // frag-read xor (row&7)
  const int L = blockIdx.x;
  const int xcd = L & 7, s = L >> 3;            // s: 0..143, m fastest (n-major)
  const int m0 = (xcd * 8 + (s & 7)) * 128;
  const int n0 = (s >> 3) * 128;
  const bool sw = (n0 < 1536);                  // q/k: swapped operands
  const unsigned short* Ab = sw ? wb : xb;
  const unsigned short* Bb = sw ? xb : wb;
  const int Ao = sw ? n0 : m0;
  const int Bo = sw ? m0 : n0;
  const int srow = lane >> 3;                   // 0..7, == row&7 of staged row
  const int scolsw = ((lane & 7) ^ srow) * 8;   // swizzled source chunk
  const unsigned short* ga = Ab + (size_t)(Ao + wid * 32 + srow) * 768 + scolsw;
  const unsigned short* gb = Bb + (size_t)(Bo + wid * 32 + srow) * 768 + scolsw;
  f32x4 acc[4][4] = {};

  for (int kt = 0; kt < 768; kt += 64) {
#pragma unroll
    for (int i = 0; i < 4; ++i) {
      gl_lds16(ga + kt + (size_t)i * 8 * 768, &smem[(wid * 32 + i * 8) * 64]);
      gl_lds16(gb + kt + (size_t)i * 8 * 768, &smem[8192 + (wid * 32 + i * 8) * 64]);
    }
    __syncthreads();
#pragma unroll
    for (int ks = 0; ks < 2; ++ks) {
      bf16x8 af[4], bf[4];
#pragma unroll
      for (int i = 0; i < 4; ++i)
        af[i] = *(const bf16x8*)&smem[(wm + i * 16 + lm) * 64 + (((ks * 4 + lq) ^ xsw) * 8)];
#pragma unroll
      for (int i = 0; i < 4; ++i)
        bf[i] = *(const bf16x8*)&smem[8192 + (wn + i * 16 + lm) * 64 + (((ks * 4 + lq) ^ xsw) * 8)];
#pragma unroll
      for (int mi = 0; mi < 4; ++mi)
#pragma unroll
        for (int ni = 0; ni < 4; ++ni)
          acc[mi][ni] = __builtin_amdgcn_mfma_f32_16x16x32_bf16(af[mi], bf[ni], acc[mi][ni], 0, 0, 0);
    }
    __syncthreads();
  }

  if (sw) {
    // acc rows = d_local (0..127), cols = tok_local (0..127); scratch[tok][d]
    const int which = (n0 >= 768) ? 1 : 0;       // 0=q, 1=k
    const int within0 = n0 - which * 768;
#pragma unroll
    for (int mi = 0; mi < 4; ++mi) {
      int d0 = wm + mi * 16 + lq * 4;
      f32x4 bias4 = {0.f, 0.f, 0.f, 0.f};
      if (which == 0) bias4 = *(const f32x4*)&qb[within0 + d0];
#pragma unroll
      for (int ni = 0; ni < 4; ++ni) {
        int tokl = wn + ni * 16 + lm;
        uint2v pk;
        if (which == 0) {
          pk.x = pack2bf((acc[mi][ni][0] + bias4[0]) * QK_PRESCALE,
                         (acc[mi][ni][1] + bias4[1]) * QK_PRESCALE);
          pk.y = pack2bf((acc[mi][ni][2] + bias4[2]) * QK_PRESCALE,
                         (acc[mi][ni][3] + bias4[3]) * QK_PRESCALE);
        } else {
          pk.x = pack2bf(acc[mi][ni][0], acc[mi][ni][1]);
          pk.y = pack2bf(acc[mi][ni][2], acc[mi][ni][3]);
        }
        *(uint2v*)&smem[tokl * 136 + d0] = pk;
      }
    }
    __syncthreads();
    // coalesced readout: thread -> (tok = tid>>1, head-half = tid&1)
    {
      int tok = tid >> 1, half = tid & 1;
      int b = m0 >> 10;
      int tokg = (m0 & 1023) + tok;
      int hh = (within0 >> 6) + half;
      unsigned short* dst = which ? ko : qo;
      size_t base = (((size_t)(b * 12 + hh)) * 1024 + tokg) * 64;
      const unsigned short* srcr = &smem[tok * 136 + half * 64];
#pragma unroll
      for (int j = 0; j < 8; ++j)
        *(uint4v*)&dst[base + j * 8] = *(const uint4v*)&srcr[j * 8];
    }
  } else {
    // v: acc rows = tok_local, cols = d_local; scratch[d][tok]
    const int within0 = n0 - 1536;
#pragma unroll
    for (int mi = 0; mi < 4; ++mi) {
      int tok0 = wm + mi * 16 + lq * 4;
#pragma unroll
      for (int ni = 0; ni < 4; ++ni) {
        int dl = wn + ni * 16 + lm;
        float bias = vb[within0 + dl];
        uint2v pk;
        pk.x = pack2bf(acc[mi][ni][0] + bias, acc[mi][ni][1] + bias);
        pk.y = pack2bf(acc[mi][ni][2] + bias, acc[mi][ni][3] + bias);
        *(uint2v*)&smem[dl * 136 + tok0] = pk;
      }
    }
    __syncthreads();
    // readout: thread -> (d_local = tid>>1, token-half = tid&1); contiguous toks
    {
      int dl = tid >> 1, halft = tid & 1;
      int within = within0 + dl;
      int hh = within >> 6, d = within & 63;
      int b = m0 >> 10;
      int tokg0 = (m0 & 1023) + halft * 64;
      size_t base = (((size_t)(b * 12 + hh)) * 64 + d) * 1024 + tokg0;
      const unsigned short* srcr = &smem[dl * 136 + halft * 64];
#pragma unroll
      for (int j = 0; j < 8; ++j)
        *(uint4v*)&vto[base + j * 8] = *(const uint4v*)&srcr[j * 8];
    }
  }
}

// ---------------------------------------------------------------------------
// Flash attention. 768 blocks = 8 XCD x (12 bh x 8 q-tiles).
// S^T = K Q^T (lane holds 4 consecutive keys -> packed P writes via v_perm).
// K/V tiles LDS double-buffered (direct-indexed), ONE barrier per K-tile.
// Fixed-max exp2 softmax; l via MFMA against ones.  Staging XOR-swizzled.
// ---------------------------------------------------------------------------
__global__ __launch_bounds__(256)
void attn_mfma(const unsigned short* __restrict__ q, const unsigned short* __restrict__ k,
               const unsigned short* __restrict__ vt, const int* __restrict__ mask,
               unsigned short* __restrict__ ao) {
  __shared__ unsigned short ks_s[2 * 4096];    // [buf][key][hd], swizzled chunks
  __shared__ unsigned short vs_s[2 * 4096];    // [buf][hd][key], swizzled chunks
  __shared__ unsigned short ps[4][32 * 72];    // per-wave P [q][key], stride 72
  __shared__ float mkl[2][64];                 // double-buffered mask row
  const int tid = threadIdx.x;
  const int lane = tid & 63, wid = tid >> 6;
  const int lm = lane & 15, lq = lane >> 4;
  const int xsw = lm & 7;
  const int L = blockIdx.x;
  const int xcd = L & 7, s = L >> 3;           // s: 0..95
  const int bh = xcd * 12 + s / 8;
  const int qt = s % 8;
  const int bb = bh / 12, hh = bh % 12;
  const unsigned short* qp = q + (size_t)bh * 65536;
  const unsigned short* kp = k + (size_t)bh * 65536;
  const unsigned short* vp = vt + (size_t)bh * 65536;
  const int* mp = mask + bb * 1024;
  const int q0 = qt * 128 + wid * 32;
  const int srow = lane >> 3;
  const int scolsw = ((lane & 7) ^ srow) * 8;
  const unsigned short* gk = kp + (size_t)(wid * 16 + srow) * 64 + scolsw;
  const unsigned short* gv = vp + (size_t)(wid * 16 + srow) * 1024 + scolsw;

  bf16x8 qf[2][2];
#pragma unroll
  for (int mi = 0; mi < 2; ++mi)
#pragma unroll
    for (int ks2 = 0; ks2 < 2; ++ks2)
      qf[mi][ks2] = *(const bf16x8*)&qp[(size_t)(q0 + mi * 16 + lm) * 64 + ks2 * 32 + lq * 8];
  bf16x8 ones;
#pragma unroll
  for (int i = 0; i < 8; ++i) ones[i] = (__bf16)1.0f;

  f32x4 o_acc[2][4] = {};
  f32x4 l_acc[2] = {};

  // prologue: stage tile 0 into buffer 0
#pragma unroll
  for (int i = 0; i < 2; ++i) {
    gl_lds16(gk + (size_t)i * 8 * 64, &ks_s[(wid * 16 + i * 8) * 64]);
    gl_lds16(gv + (size_t)i * 8 * 1024, &vs_s[(wid * 16 + i * 8) * 64]);
  }
  if (tid < 64) mkl[0][tid] = mp[tid] ? -1e30f : 0.0f;
  __syncthreads();

  for (int kt = 0; kt < 16; ++kt) {
    const int cur = kt & 1, nxt = cur ^ 1;
    if (kt < 15) {                             // prefetch next tile into other buffer
#pragma unroll
      for (int i = 0; i < 2; ++i) {
        gl_lds16(gk + (size_t)(kt + 1) * 4096 + (size_t)i * 8 * 64,
                 &ks_s[nxt * 4096 + (wid * 16 + i * 8) * 64]);
        gl_lds16(gv + (size_t)(kt + 1) * 64 + (size_t)i * 8 * 1024,
                 &vs_s[nxt * 4096 + (wid * 16 + i * 8) * 64]);
      }
      if (tid < 64) mkl[nxt][tid] = mp[(kt + 1) * 64 + tid] ? -1e30f : 0.0f;
    }

    // S^T = K Q^T : tile [key-tile nt][q-tile mi]; col=q=lm, row=key=lq*4+r
    f32x4 st[4][2] = {};
#pragma unroll
    for (int ks2 = 0; ks2 < 2; ++ks2) {
      bf16x8 kf[4];
#pragma unroll
      for (int nt = 0; nt < 4; ++nt)
        kf[nt] = *(const bf16x8*)&ks_s[cur * 4096 + (nt * 16 + lm) * 64 + (((ks2 * 4 + lq) ^ xsw) * 8)];
#pragma unroll
      for (int nt = 0; nt < 4; ++nt)
#pragma unroll
        for (int mi = 0; mi < 2; ++mi)
          st[nt][mi] = __builtin_amdgcn_mfma_f32_16x16x32_bf16(kf[nt], qf[mi][ks2], st[nt][mi], 0, 0, 0);
    }

    // p = exp2(st + mask[key]); v_perm packed writes into A-layout P buffer
#pragma unroll
    for (int nt = 0; nt < 4; ++nt) {
      f32x4 mv4 = *(const f32x4*)&mkl[cur][nt * 16 + lq * 4];
#pragma unroll
      for (int mi = 0; mi < 2; ++mi) {
        uint2v pk;
        pk.x = pack2bf(exp2f(st[nt][mi][0] + mv4[0]), exp2f(st[nt][mi][1] + mv4[1]));
        pk.y = pack2bf(exp2f(st[nt][mi][2] + mv4[2]), exp2f(st[nt][mi][3] + mv4[3]));
        *(uint2v*)&ps[wid][(mi * 16 + lm) * 72 + nt * 16 + lq * 4] = pk;
      }
    }

    // O += P V ; l += P . 1   (ps wave-private: no barrier)
#pragma unroll
    for (int ks2 = 0; ks2 < 2; ++ks2) {
      bf16x8 pf[2], vf[4];
#pragma unroll
      for (int mi = 0; mi < 2; ++mi)
        pf[mi] = *(const bf16x8*)&ps[wid][(mi * 16 + lm) * 72 + ks2 * 32 + lq * 8];
#pragma unroll
      for (int nt = 0; nt < 4; ++nt)
        vf[nt] = *(const bf16x8*)&vs_s[cur * 4096 + (nt * 16 + lm) * 64 + (((ks2 * 4 + lq) ^ xsw) * 8)];
#pragma unroll
      for (int mi = 0; mi < 2; ++mi) {
#pragma unroll
        for (int nt = 0; nt < 4; ++nt)
          o_acc[mi][nt] = __builtin_amdgcn_mfma_f32_16x16x32_bf16(pf[mi], vf[nt], o_acc[mi][nt], 0, 0, 0);
        l_acc[mi] = __builtin_amdgcn_mfma_f32_16x16x32_bf16(pf[mi], ones, l_acc[mi], 0, 0, 0);
      }
    }
    __syncthreads();   // drains prefetch (vmcnt) + all waves done reading cur
  }

  // epilogue: ao[b, tok, h*64+d] = O/l  (bf16)
#pragma unroll
  for (int mi = 0; mi < 2; ++mi) {
#pragma unroll
    for (int r = 0; r < 4; ++r) {
      float inv = 1.0f / l_acc[mi][r];
      int tok = q0 + mi * 16 + lq * 4 + r;
#pragma unroll
      for (int nt = 0; nt < 4; ++nt)
        ao[(size_t)(bb * 1024 + tok) * 768 + hh * 64 + nt * 16 + lm] = f2bf(o_acc[mi][nt][r] * inv);
    }
  }
}

// ---------------------------------------------------------------------------
// Proj GEMM: M=8192, N=768, K=768.  Operands swapped (A=w, B=ao); swizzled.
// 384 blocks = 8 XCD x (8 m x 6 n).
// ---------------------------------------------------------------------------
__global__ __launch_bounds__(256)
void proj_gemm(const unsigned short* __restrict__ ab, const unsigned short* __restrict__ wb,
               const float* __restrict__ pb, float* __restrict__ out) {
  __shared__ unsigned short as[128 * 64];   // w rows
  __shared__ unsigned short bs[128 * 64];   // ao rows
  const int tid = threadIdx.x;
  const int lane = tid & 63, wid = tid >> 6;
  const int lm = lane & 15, lq = lane >> 4;
  const int xsw = lm & 7;
  const int wm = (wid & 1) * 64, wn = (wid >> 1) * 64;
  const int L = blockIdx.x;
  const int xcd = L & 7, s = L >> 3;           // s: 0..47
  const int m0 = (xcd * 8 + s / 6) * 128;
  const int n0 = (s % 6) * 128;
  const int srow = lane >> 3;
  const int scolsw = ((lane & 7) ^ srow) * 8;
  const unsigned short* ga = wb + (size_t)(n0 + wid * 32 + srow) * 768 + scolsw;
  const unsigned short* gb = ab + (size_t)(m0 + wid * 32 + srow) * 768 + scolsw;
  f32x4 acc[4][4] = {};
  for (int kt = 0; kt < 768; kt += 64) {
#pragma unroll
    for (int i = 0; i < 4; ++i) {
      gl_lds16(ga + kt + (size_t)i * 8 * 768, &as[(wid * 32 + i * 8) * 64]);
      gl_lds16(gb + kt + (size_t)i * 8 * 768, &bs[(wid * 32 + i * 8) * 64]);
    }
    __syncthreads();
#pragma unroll
    for (int ks = 0; ks < 2; ++ks) {
      bf16x8 af[4], bf[4];
#pragma unroll
      for (int i = 0; i < 4; ++i)
        af[i] = *(const bf16x8*)&as[(wm + i * 16 + lm) * 64 + (((ks * 4 + lq) ^ xsw) * 8)];
#pragma unroll
      for (int i = 0; i < 4; ++i)
        bf[i] = *(const bf16x8*)&bs[(wn + i * 16 + lm) * 64 + (((ks * 4 + lq) ^ xsw) * 8)];
#pragma unroll
      for (int mi = 0; mi < 4; ++mi)
#pragma unroll
        for (int ni = 0; ni < 4; ++ni)
          acc[mi][ni] = __builtin_amdgcn_mfma_f32_16x16x32_bf16(af[mi], bf[ni], acc[mi][ni], 0, 0, 0);
    }
    __syncthreads();
  }
  // acc rows = n-dim, cols = m-dim
#pragma unroll
  for (int mi = 0; mi < 4; ++mi) {
    int gn0 = n0 + wm + mi * 16 + lq * 4;
    f32x4 bias4 = *(const f32x4*)&pb[gn0];
#pragma unroll
    for (int ni = 0; ni < 4; ++ni) {
      int gm = m0 + wn + ni * 16 + lm;
      f32x4 o;
      o[0] = acc[mi][ni][0] + bias4[0];
      o[1] = acc[mi][ni][1] + bias4[1];
      o[2] = acc[mi][ni][2] + bias4[2];
      o[3] = acc[mi][ni][3] + bias4[3];
      *(f32x4*)&out[(size_t)gm * 768 + gn0] = o;
    }
  }
}

// ---------------------------------------------------------------------------
// ws layout (bf16 elts): xb 6291456 | wqkv 1769472 | wproj 589824 |
//   q 6291456 | k 6291456 | v^T 6291456 | ao 6291456   (~67.6 MB)
// ---------------------------------------------------------------------------
extern "C" void kernel_launch(void* const* d_in, const int* in_sizes, int n_in,
                              void* d_out, int out_size, void* d_ws, size_t ws_size,
                              hipStream_t stream) {
  const float* x      = (const float*)d_in[0];
  const int*   mask   = (const int*)d_in[1];
  const float* qkv_w  = (const float*)d_in[2];
  const float* q_bias = (const float*)d_in[3];
  const float* v_bias = (const float*)d_in[4];
  const float* proj_w = (const float*)d_in[5];
  const float* proj_b = (const float*)d_in[6];
  float* out = (float*)d_out;
  unsigned short* p = (unsigned short*)d_ws;
  unsigned short* xb     = p;              p += 6291456;
  unsigned short* wqkvb  = p;              p += 1769472;
  unsigned short* wprojb = p;              p += 589824;
  unsigned short* qo     = p;              p += 6291456;
  unsigned short* ko     = p;              p += 6291456;
  unsigned short* vto    = p;              p += 6291456;
  unsigned short* ao     = p;

  cvt_kernel<<<6144, 256, 0, stream>>>(x, xb, 1572864);
  cvt_kernel<<<1728, 256, 0, stream>>>(qkv_w, wqkvb, 442368);
  cvt_kernel<<<576, 256, 0, stream>>>(proj_w, wprojb, 147456);
  qkv_gemm<<<1152, 256, 0, stream>>>(xb, wqkvb, q_bias, v_bias, qo, ko, vto);
  attn_mfma<<<768, 256, 0, stream>>>(qo, ko, vto, mask, ao);
  proj_gemm<<<384, 256, 0, stream>>>(ao, wprojb, proj_b, out);
}

// Round 9
// 208.452 us; speedup vs baseline: 1.0730x; 1.0730x over previous
//
#include <hip/hip_runtime.h>
#include <cstddef>
#include <cstdint>

// ---------------------------------------------------------------------------
// B=8, N=1024, C=768, H=12, hd=64.  All matmuls mfma_f32_16x16x32_bf16.
// R8: attn back to single-buffer K/V staging (R7 dbuf lost occupancy ->
// regression), keeps v_perm packed bf16 P-writes, and replaces libm exp2f
// (~8 VALU insts, no fast-math) with raw v_exp_f32 via
// __builtin_amdgcn_exp2f (1 inst; masked -1e30 underflows to +0).
// qkv/proj unchanged from R7 (R6 structure + pack2bf epilogues).
// ---------------------------------------------------------------------------

typedef __attribute__((ext_vector_type(4))) float f32x4;
typedef __attribute__((ext_vector_type(8))) __bf16 bf16x8;
typedef __attribute__((ext_vector_type(4))) unsigned int uint4v;
typedef __attribute__((ext_vector_type(2))) unsigned int uint2v;
typedef __attribute__((ext_vector_type(4))) unsigned short ushort4v;

#define QK_PRESCALE 0.18033688011112042f   // 64^-0.5 * log2(e); softmax uses exp2

// round-half-up bf16: max error 0.5 ulp (ties round up instead of to-even)
__device__ __forceinline__ unsigned short f2bf(float f) {
  return (unsigned short)((__float_as_uint(f) + 0x8000u) >> 16);
}
// pack two floats -> bf16x2 in one v_perm_b32: (bf(fhi)<<16) | bf(flo)
__device__ __forceinline__ unsigned int pack2bf(float flo, float fhi) {
  unsigned ulo = __float_as_uint(flo) + 0x8000u;
  unsigned uhi = __float_as_uint(fhi) + 0x8000u;
  return __builtin_amdgcn_perm(uhi, ulo, 0x07060302);
}

// one wave instruction: 64 lanes x 16 B -> LDS[base + lane*16]
__device__ __forceinline__ void gl_lds16(const unsigned short* g, unsigned short* l) {
  __builtin_amdgcn_global_load_lds(
      (const __attribute__((address_space(1))) unsigned int*)g,
      (__attribute__((address_space(3))) unsigned int*)l, 16, 0, 0);
}

// ---------------------------------------------------------------------------
// fp32 -> bf16 conversion, 4 elements/thread
// ---------------------------------------------------------------------------
__global__ __launch_bounds__(256)
void cvt_kernel(const float* __restrict__ src, unsigned short* __restrict__ dst, int n4) {
  int i = blockIdx.x * 256 + threadIdx.x;
  if (i < n4) {
    float4 v = ((const float4*)src)[i];
    uint2v o;
    o.x = pack2bf(v.x, v.y);
    o.y = pack2bf(v.z, v.w);
    ((uint2v*)dst)[i] = o;
  }
}

// ---------------------------------------------------------------------------
// QKV GEMM: M=8192, N=2304, K=768. 128x128 tile, BK=64, 4 waves.
// 1152 blocks = 8 XCD x (18 n-tiles x 8 m-tiles, m fastest).
// q/k tiles (n0 < 1536): operands swapped (A=w, B=x) -> acc rows=d, cols=tok.
// v tiles: unswapped -> acc rows=tok, cols=d.
// Staging XOR-swizzled; epilogue via LDS scratch (stride 136) -> b128 stores.
// ---------------------------------------------------------------------------
__global__ __launch_bounds__(256)
void qkv_gemm(const unsigned short* __restrict__ xb, const unsigned short* __restrict__ wb,
              const float* __restrict__ qb, const float* __restrict__ vb,
              unsigned short* __restrict__ qo, unsigned short* __restrict__ ko,
              unsigned short* __restrict__ vto) {
  __shared__ __align__(16) unsigned short smem[17408];  // as[0..8191] bs[8192..16383]; scratch 128x136
  const int tid = threadIdx.x;
  const int lane = tid & 63, wid = tid >> 6;
  const int lm = lane & 15, lq = lane >> 4;
  const int wm = (wid & 1) * 64, wn = (wid >> 1) * 64;
  const int xsw = lm & 7;                       // frag-read xor (row&7)
  const int L = blockIdx.x;
  const int xcd = L & 7, s = L >> 3;            // s: 0..143, m fastest (n-major)
  const int m0 = (xcd * 8 + (s & 7)) * 128;
  const int n0 = (s >> 3) * 128;
  const bool sw = (n0 < 1536);                  // q/k: swapped operands
  const unsigned short* Ab = sw ? wb : xb;
  const unsigned short* Bb = sw ? xb : wb;
  const int Ao = sw ? n0 : m0;
  const int Bo = sw ? m0 : n0;
  const int srow = lane >> 3;                   // 0..7, == row&7 of staged row
  const int scolsw = ((lane & 7) ^ srow) * 8;   // swizzled source chunk
  const unsigned short* ga = Ab + (size_t)(Ao + wid * 32 + srow) * 768 + scolsw;
  const unsigned short* gb = Bb + (size_t)(Bo + wid * 32 + srow) * 768 + scolsw;
  f32x4 acc[4][4] = {};

  for (int kt = 0; kt < 768; kt += 64) {
#pragma unroll
    for (int i = 0; i < 4; ++i) {
      gl_lds16(ga + kt + (size_t)i * 8 * 768, &smem[(wid * 32 + i * 8) * 64]);
      gl_lds16(gb + kt + (size_t)i * 8 * 768, &smem[8192 + (wid * 32 + i * 8) * 64]);
    }
    __syncthreads();
#pragma unroll
    for (int ks = 0; ks < 2; ++ks) {
      bf16x8 af[4], bf[4];
#pragma unroll
      for (int i = 0; i < 4; ++i)
        af[i] = *(const bf16x8*)&smem[(wm + i * 16 + lm) * 64 + (((ks * 4 + lq) ^ xsw) * 8)];
#pragma unroll
      for (int i = 0; i < 4; ++i)
        bf[i] = *(const bf16x8*)&smem[8192 + (wn + i * 16 + lm) * 64 + (((ks * 4 + lq) ^ xsw) * 8)];
#pragma unroll
      for (int mi = 0; mi < 4; ++mi)
#pragma unroll
        for (int ni = 0; ni < 4; ++ni)
          acc[mi][ni] = __builtin_amdgcn_mfma_f32_16x16x32_bf16(af[mi], bf[ni], acc[mi][ni], 0, 0, 0);
    }
    __syncthreads();
  }

  if (sw) {
    // acc rows = d_local (0..127), cols = tok_local (0..127); scratch[tok][d]
    const int which = (n0 >= 768) ? 1 : 0;       // 0=q, 1=k
    const int within0 = n0 - which * 768;
#pragma unroll
    for (int mi = 0; mi < 4; ++mi) {
      int d0 = wm + mi * 16 + lq * 4;
      f32x4 bias4 = {0.f, 0.f, 0.f, 0.f};
      if (which == 0) bias4 = *(const f32x4*)&qb[within0 + d0];
#pragma unroll
      for (int ni = 0; ni < 4; ++ni) {
        int tokl = wn + ni * 16 + lm;
        uint2v pk;
        if (which == 0) {
          pk.x = pack2bf((acc[mi][ni][0] + bias4[0]) * QK_PRESCALE,
                         (acc[mi][ni][1] + bias4[1]) * QK_PRESCALE);
          pk.y = pack2bf((acc[mi][ni][2] + bias4[2]) * QK_PRESCALE,
                         (acc[mi][ni][3] + bias4[3]) * QK_PRESCALE);
        } else {
          pk.x = pack2bf(acc[mi][ni][0], acc[mi][ni][1]);
          pk.y = pack2bf(acc[mi][ni][2], acc[mi][ni][3]);
        }
        *(uint2v*)&smem[tokl * 136 + d0] = pk;
      }
    }
    __syncthreads();
    // coalesced readout: thread -> (tok = tid>>1, head-half = tid&1)
    {
      int tok = tid >> 1, half = tid & 1;
      int b = m0 >> 10;
      int tokg = (m0 & 1023) + tok;
      int hh = (within0 >> 6) + half;
      unsigned short* dst = which ? ko : qo;
      size_t base = (((size_t)(b * 12 + hh)) * 1024 + tokg) * 64;
      const unsigned short* srcr = &smem[tok * 136 + half * 64];
#pragma unroll
      for (int j = 0; j < 8; ++j)
        *(uint4v*)&dst[base + j * 8] = *(const uint4v*)&srcr[j * 8];
    }
  } else {
    // v: acc rows = tok_local, cols = d_local; scratch[d][tok]
    const int within0 = n0 - 1536;
#pragma unroll
    for (int mi = 0; mi < 4; ++mi) {
      int tok0 = wm + mi * 16 + lq * 4;
#pragma unroll
      for (int ni = 0; ni < 4; ++ni) {
        int dl = wn + ni * 16 + lm;
        float bias = vb[within0 + dl];
        uint2v pk;
        pk.x = pack2bf(acc[mi][ni][0] + bias, acc[mi][ni][1] + bias);
        pk.y = pack2bf(acc[mi][ni][2] + bias, acc[mi][ni][3] + bias);
        *(uint2v*)&smem[dl * 136 + tok0] = pk;
      }
    }
    __syncthreads();
    // readout: thread -> (d_local = tid>>1, token-half = tid&1); contiguous toks
    {
      int dl = tid >> 1, halft = tid & 1;
      int within = within0 + dl;
      int hh = within >> 6, d = within & 63;
      int b = m0 >> 10;
      int tokg0 = (m0 & 1023) + halft * 64;
      size_t base = (((size_t)(b * 12 + hh)) * 64 + d) * 1024 + tokg0;
      const unsigned short* srcr = &smem[dl * 136 + halft * 64];
#pragma unroll
      for (int j = 0; j < 8; ++j)
        *(uint4v*)&vto[base + j * 8] = *(const uint4v*)&srcr[j * 8];
    }
  }
}

// ---------------------------------------------------------------------------
// Flash attention. 768 blocks = 8 XCD x (12 bh x 8 q-tiles).
// S^T = K Q^T so each lane holds 4 consecutive keys -> v_perm packed P writes.
// Fixed-max softmax via raw v_exp_f32; l via MFMA against ones.
// Single-buffer staging (XOR-swizzled); 2 barriers/K-tile.
// ---------------------------------------------------------------------------
__global__ __launch_bounds__(256)
void attn_mfma(const unsigned short* __restrict__ q, const unsigned short* __restrict__ k,
               const unsigned short* __restrict__ vt, const int* __restrict__ mask,
               unsigned short* __restrict__ ao) {
  __shared__ unsigned short ks_s[64 * 64];     // [key][hd], swizzled chunks
  __shared__ unsigned short vs_s[64 * 64];     // [hd][key], swizzled chunks
  __shared__ unsigned short ps[4][32 * 72];    // per-wave P [q][key], stride 72
  __shared__ float mkl[64];
  const int tid = threadIdx.x;
  const int lane = tid & 63, wid = tid >> 6;
  const int lm = lane & 15, lq = lane >> 4;
  const int xsw = lm & 7;
  const int L = blockIdx.x;
  const int xcd = L & 7, s = L >> 3;           // s: 0..95
  const int bh = xcd * 12 + s / 8;
  const int qt = s % 8;
  const int bb = bh / 12, hh = bh % 12;
  const unsigned short* qp = q + (size_t)bh * 65536;
  const unsigned short* kp = k + (size_t)bh * 65536;
  const unsigned short* vp = vt + (size_t)bh * 65536;
  const int* mp = mask + bb * 1024;
  const int q0 = qt * 128 + wid * 32;
  const int srow = lane >> 3;
  const int scolsw = ((lane & 7) ^ srow) * 8;
  const unsigned short* gk = kp + (size_t)(wid * 16 + srow) * 64 + scolsw;
  const unsigned short* gv = vp + (size_t)(wid * 16 + srow) * 1024 + scolsw;

  bf16x8 qf[2][2];
#pragma unroll
  for (int mi = 0; mi < 2; ++mi)
#pragma unroll
    for (int ks2 = 0; ks2 < 2; ++ks2)
      qf[mi][ks2] = *(const bf16x8*)&qp[(size_t)(q0 + mi * 16 + lm) * 64 + ks2 * 32 + lq * 8];
  bf16x8 ones;
#pragma unroll
  for (int i = 0; i < 8; ++i) ones[i] = (__bf16)1.0f;

  f32x4 o_acc[2][4] = {};
  f32x4 l_acc[2] = {};

  for (int kt = 0; kt < 16; ++kt) {
    __syncthreads();                           // drain prior tile reads
#pragma unroll
    for (int i = 0; i < 2; ++i) {
      gl_lds16(gk + (size_t)kt * 4096 + (size_t)i * 8 * 64, &ks_s[(wid * 16 + i * 8) * 64]);
      gl_lds16(gv + (size_t)kt * 64 + (size_t)i * 8 * 1024, &vs_s[(wid * 16 + i * 8) * 64]);
    }
    if (tid < 64) mkl[tid] = mp[kt * 64 + tid] ? -1e30f : 0.0f;
    __syncthreads();

    // S^T = K Q^T : tile [key-tile nt][q-tile mi]; col=q=lm, row=key=lq*4+r
    f32x4 st[4][2] = {};
#pragma unroll
    for (int ks2 = 0; ks2 < 2; ++ks2) {
      bf16x8 kf[4];
#pragma unroll
      for (int nt = 0; nt < 4; ++nt)
        kf[nt] = *(const bf16x8*)&ks_s[(nt * 16 + lm) * 64 + (((ks2 * 4 + lq) ^ xsw) * 8)];
#pragma unroll
      for (int nt = 0; nt < 4; ++nt)
#pragma unroll
        for (int mi = 0; mi < 2; ++mi)
          st[nt][mi] = __builtin_amdgcn_mfma_f32_16x16x32_bf16(kf[nt], qf[mi][ks2], st[nt][mi], 0, 0, 0);
    }

    // p = exp2(st + mask[key]) via raw v_exp_f32; packed b64 P writes
#pragma unroll
    for (int nt = 0; nt < 4; ++nt) {
      f32x4 mv4 = *(const f32x4*)&mkl[nt * 16 + lq * 4];
#pragma unroll
      for (int mi = 0; mi < 2; ++mi) {
        uint2v pk;
        pk.x = pack2bf(__builtin_amdgcn_exp2f(st[nt][mi][0] + mv4[0]),
                       __builtin_amdgcn_exp2f(st[nt][mi][1] + mv4[1]));
        pk.y = pack2bf(__builtin_amdgcn_exp2f(st[nt][mi][2] + mv4[2]),
                       __builtin_amdgcn_exp2f(st[nt][mi][3] + mv4[3]));
        *(uint2v*)&ps[wid][(mi * 16 + lm) * 72 + nt * 16 + lq * 4] = pk;
      }
    }

    // O += P V ; l += P . 1   (ps wave-private: no barrier)
#pragma unroll
    for (int ks2 = 0; ks2 < 2; ++ks2) {
      bf16x8 pf[2], vf[4];
#pragma unroll
      for (int mi = 0; mi < 2; ++mi)
        pf[mi] = *(const bf16x8*)&ps[wid][(mi * 16 + lm) * 72 + ks2 * 32 + lq * 8];
#pragma unroll
      for (int nt = 0; nt < 4; ++nt)
        vf[nt] = *(const bf16x8*)&vs_s[(nt * 16 + lm) * 64 + (((ks2 * 4 + lq) ^ xsw) * 8)];
#pragma unroll
      for (int mi = 0; mi < 2; ++mi) {
#pragma unroll
        for (int nt = 0; nt < 4; ++nt)
          o_acc[mi][nt] = __builtin_amdgcn_mfma_f32_16x16x32_bf16(pf[mi], vf[nt], o_acc[mi][nt], 0, 0, 0);
        l_acc[mi] = __builtin_amdgcn_mfma_f32_16x16x32_bf16(pf[mi], ones, l_acc[mi], 0, 0, 0);
      }
    }
  }

  // epilogue: ao[b, tok, h*64+d] = O/l  (bf16)
#pragma unroll
  for (int mi = 0; mi < 2; ++mi) {
#pragma unroll
    for (int r = 0; r < 4; ++r) {
      float inv = 1.0f / l_acc[mi][r];
      int tok = q0 + mi * 16 + lq * 4 + r;
#pragma unroll
      for (int nt = 0; nt < 4; ++nt)
        ao[(size_t)(bb * 1024 + tok) * 768 + hh * 64 + nt * 16 + lm] = f2bf(o_acc[mi][nt][r] * inv);
    }
  }
}

// ---------------------------------------------------------------------------
// Proj GEMM: M=8192, N=768, K=768.  Operands swapped (A=w, B=ao); swizzled.
// 384 blocks = 8 XCD x (8 m x 6 n).
// ---------------------------------------------------------------------------
__global__ __launch_bounds__(256)
void proj_gemm(const unsigned short* __restrict__ ab, const unsigned short* __restrict__ wb,
               const float* __restrict__ pb, float* __restrict__ out) {
  __shared__ unsigned short as[128 * 64];   // w rows
  __shared__ unsigned short bs[128 * 64];   // ao rows
  const int tid = threadIdx.x;
  const int lane = tid & 63, wid = tid >> 6;
  const int lm = lane & 15, lq = lane >> 4;
  const int xsw = lm & 7;
  const int wm = (wid & 1) * 64, wn = (wid >> 1) * 64;
  const int L = blockIdx.x;
  const int xcd = L & 7, s = L >> 3;           // s: 0..47
  const int m0 = (xcd * 8 + s / 6) * 128;
  const int n0 = (s % 6) * 128;
  const int srow = lane >> 3;
  const int scolsw = ((lane & 7) ^ srow) * 8;
  const unsigned short* ga = wb + (size_t)(n0 + wid * 32 + srow) * 768 + scolsw;
  const unsigned short* gb = ab + (size_t)(m0 + wid * 32 + srow) * 768 + scolsw;
  f32x4 acc[4][4] = {};
  for (int kt = 0; kt < 768; kt += 64) {
#pragma unroll
    for (int i = 0; i < 4; ++i) {
      gl_lds16(ga + kt + (size_t)i * 8 * 768, &as[(wid * 32 + i * 8) * 64]);
      gl_lds16(gb + kt + (size_t)i * 8 * 768, &bs[(wid * 32 + i * 8) * 64]);
    }
    __syncthreads();
#pragma unroll
    for (int ks = 0; ks < 2; ++ks) {
      bf16x8 af[4], bf[4];
#pragma unroll
      for (int i = 0; i < 4; ++i)
        af[i] = *(const bf16x8*)&as[(wm + i * 16 + lm) * 64 + (((ks * 4 + lq) ^ xsw) * 8)];
#pragma unroll
      for (int i = 0; i < 4; ++i)
        bf[i] = *(const bf16x8*)&bs[(wn + i * 16 + lm) * 64 + (((ks * 4 + lq) ^ xsw) * 8)];
#pragma unroll
      for (int mi = 0; mi < 4; ++mi)
#pragma unroll
        for (int ni = 0; ni < 4; ++ni)
          acc[mi][ni] = __builtin_amdgcn_mfma_f32_16x16x32_bf16(af[mi], bf[ni], acc[mi][ni], 0, 0, 0);
    }
    __syncthreads();
  }
  // acc rows = n-dim, cols = m-dim
#pragma unroll
  for (int mi = 0; mi < 4; ++mi) {
    int gn0 = n0 + wm + mi * 16 + lq * 4;
    f32x4 bias4 = *(const f32x4*)&pb[gn0];
#pragma unroll
    for (int ni = 0; ni < 4; ++ni) {
      int gm = m0 + wn + ni * 16 + lm;
      f32x4 o;
      o[0] = acc[mi][ni][0] + bias4[0];
      o[1] = acc[mi][ni][1] + bias4[1];
      o[2] = acc[mi][ni][2] + bias4[2];
      o[3] = acc[mi][ni][3] + bias4[3];
      *(f32x4*)&out[(size_t)gm * 768 + gn0] = o;
    }
  }
}

// ---------------------------------------------------------------------------
// ws layout (bf16 elts): xb 6291456 | wqkv 1769472 | wproj 589824 |
//   q 6291456 | k 6291456 | v^T 6291456 | ao 6291456   (~67.6 MB)
// ---------------------------------------------------------------------------
extern "C" void kernel_launch(void* const* d_in, const int* in_sizes, int n_in,
                              void* d_out, int out_size, void* d_ws, size_t ws_size,
                              hipStream_t stream) {
  const float* x      = (const float*)d_in[0];
  const int*   mask   = (const int*)d_in[1];
  const float* qkv_w  = (const float*)d_in[2];
  const float* q_bias = (const float*)d_in[3];
  const float* v_bias = (const float*)d_in[4];
  const float* proj_w = (const float*)d_in[5];
  const float* proj_b = (const float*)d_in[6];
  float* out = (float*)d_out;
  unsigned short* p = (unsigned short*)d_ws;
  unsigned short* xb     = p;              p += 6291456;
  unsigned short* wqkvb  = p;              p += 1769472;
  unsigned short* wprojb = p;              p += 589824;
  unsigned short* qo     = p;              p += 6291456;
  unsigned short* ko     = p;              p += 6291456;
  unsigned short* vto    = p;              p += 6291456;
  unsigned short* ao     = p;

  cvt_kernel<<<6144, 256, 0, stream>>>(x, xb, 1572864);
  cvt_kernel<<<1728, 256, 0, stream>>>(qkv_w, wqkvb, 442368);
  cvt_kernel<<<576, 256, 0, stream>>>(proj_w, wprojb, 147456);
  qkv_gemm<<<1152, 256, 0, stream>>>(xb, wqkvb, q_bias, v_bias, qo, ko, vto);
  attn_mfma<<<768, 256, 0, stream>>>(qo, ko, vto, mask, ao);
  proj_gemm<<<384, 256, 0, stream>>>(ao, wprojb, proj_b, out);
}